// Round 2
// baseline (329.000 us; speedup 1.0000x reference)
//
#include <hip/hip_runtime.h>
#include <stdint.h>

// Problem constants
#define PSIZE 26
#define DDIM  512
#define NTOK  65536   // B*S = 32*2048
#define NIT   50
#define SEPS  1e-8f

// GEMM tiling
#define BM 128
#define BN 128
#define BK 32

typedef __attribute__((ext_vector_type(4))) float f4;
typedef __attribute__((ext_vector_type(8))) short s8;   // 8 bf16 (4 VGPRs), MFMA A/B frag

// RTNE f32 -> bf16 (bit pattern)
__device__ __forceinline__ unsigned short f2bf(float f) {
    unsigned int u = __builtin_bit_cast(unsigned int, f);
    u = u + 0x7fffu + ((u >> 16) & 1u);
    return (unsigned short)(u >> 16);
}

// ---------------------------------------------------------------------------
// Kernel 1: softmax(logits) + 50 Sinkhorn iters (26x26) + pb = P @ fp_b
// One block, one wave. Lane r owns row r (r<26); col pass: lane c owns col c.
// ---------------------------------------------------------------------------
__global__ void perm_sinkhorn_kernel(const float* __restrict__ logits,
                                     const float* __restrict__ fp_b,
                                     float* __restrict__ P_out,   // [26*26]
                                     float* __restrict__ pb_out)  // [26]
{
    __shared__ float P[PSIZE][PSIZE];
    const int l = threadIdx.x;
    if (l < PSIZE) {
        float v[PSIZE];
        float mx = -1e30f;
        #pragma unroll
        for (int c = 0; c < PSIZE; ++c) { v[c] = logits[l * PSIZE + c]; mx = fmaxf(mx, v[c]); }
        float s = 0.f;
        #pragma unroll
        for (int c = 0; c < PSIZE; ++c) { v[c] = expf(v[c] - mx); s += v[c]; }
        float inv = 1.f / s;
        #pragma unroll
        for (int c = 0; c < PSIZE; ++c) P[l][c] = v[c] * inv;
    }
    __syncthreads();
    for (int it = 0; it < NIT; ++it) {
        if (l < PSIZE) {               // row normalize (axis=1)
            float s = 0.f;
            #pragma unroll
            for (int c = 0; c < PSIZE; ++c) s += P[l][c];
            float inv = 1.f / (s + SEPS);
            #pragma unroll
            for (int c = 0; c < PSIZE; ++c) P[l][c] *= inv;
        }
        __syncthreads();
        if (l < PSIZE) {               // col normalize (axis=0)
            float s = 0.f;
            #pragma unroll
            for (int r = 0; r < PSIZE; ++r) s += P[r][l];
            float inv = 1.f / (s + SEPS);
            #pragma unroll
            for (int r = 0; r < PSIZE; ++r) P[r][l] *= inv;
        }
        __syncthreads();
    }
    if (l < PSIZE) {
        float s = 0.f;
        #pragma unroll
        for (int k = 0; k < PSIZE; ++k) s += P[l][k] * fp_b[k];
        pb_out[l] = s;
        #pragma unroll
        for (int c = 0; c < PSIZE; ++c) P_out[l * PSIZE + c] = P[l][c];
    }
}

// ---------------------------------------------------------------------------
// Kernel 2: fold the three small matrices into the effective 512x512 weight.
//   g[n][k]   = sum_j op_w[n][j] * P[j][k]
//   Wt[n][d]  = sum_k g[n][k] * fp_w[k][d]        (bf16, N-major = GEMM B^T)
//   beff[n]   = sum_j pb[j] * op_w[n][j] + op_b[n]
// One block per n; thread t = d.
// ---------------------------------------------------------------------------
__global__ __launch_bounds__(512)
void weff_kernel(const float* __restrict__ fp_w,   // [26][512]
                 const float* __restrict__ op_w,   // [512][26]
                 const float* __restrict__ op_b,   // [512]
                 const float* __restrict__ Pm,     // [26][26]
                 const float* __restrict__ pb,     // [26]
                 unsigned short* __restrict__ Wt,  // [512][512] bf16 bits
                 float* __restrict__ beff)         // [512]
{
    const int n = blockIdx.x;
    const int t = threadIdx.x;
    __shared__ float ow[PSIZE];
    __shared__ float g[PSIZE];
    if (t < PSIZE) ow[t] = op_w[n * PSIZE + t];
    __syncthreads();
    if (t < PSIZE) {
        float s = 0.f;
        #pragma unroll
        for (int j = 0; j < PSIZE; ++j) s += ow[j] * Pm[j * PSIZE + t];
        g[t] = s;
    }
    __syncthreads();
    float acc = 0.f;
    #pragma unroll
    for (int k = 0; k < PSIZE; ++k) acc += g[k] * fp_w[k * DDIM + t];
    Wt[(size_t)n * DDIM + t] = f2bf(acc);
    if (t == 0) {
        float s = 0.f;
        #pragma unroll
        for (int j = 0; j < PSIZE; ++j) s += pb[j] * ow[j];
        beff[n] = s + op_b[n];
    }
}

// ---------------------------------------------------------------------------
// Kernel 3: Out[M=65536][512] = X[M][512] @ W_eff + beff  (bf16 MFMA, f32 out)
// 128x128 tile, 4 waves (2x2 of 64x64), BK=32, 16x16x32 MFMA.
// A: reg-staged f32 -> bf16 -> ds_write_b128. B: global_load_lds width=16.
// XCD-chunked swizzle, N-fastest so the 4 N-blocks sharing an A row-panel
// run on the same XCD (A L2 reuse: 128 MB HBM instead of 512 MB).
// ---------------------------------------------------------------------------
__global__ __launch_bounds__(256)
void gemm_kernel(const float* __restrict__ X,            // [65536][512] f32
                 const unsigned short* __restrict__ Wt,  // [512][512] bf16 (N-major)
                 const float* __restrict__ beff,         // [512]
                 float* __restrict__ Out)                 // [65536][512] f32
{
    __shared__ alignas(16) unsigned short Al[BM][BK];  // 8 KiB
    __shared__ alignas(16) unsigned short Bl[BN][BK];  // 8 KiB

    const int bid = blockIdx.x;
    // bijective XCD swizzle: 2048 blocks, 8 XCDs, 256-block chunks
    const int lg = (bid & 7) * 256 + (bid >> 3);
    const int nb = lg & 3;         // N-fastest: lg 4m..4m+3 share the A panel
    const int mb = lg >> 2;
    const int m_base = mb * BM;
    const int n_base = nb * BN;

    const int t    = threadIdx.x;
    const int lane = t & 63;
    const int w    = t >> 6;
    const int wr   = w >> 1;       // wave row (0/1)
    const int wc   = w & 1;        // wave col (0/1)
    const int fr   = lane & 15;    // frag row index
    const int fc   = lane >> 4;    // frag k-chunk (0..3)

    f4 acc[4][4];
    #pragma unroll
    for (int i = 0; i < 4; ++i)
        #pragma unroll
        for (int j = 0; j < 4; ++j)
            acc[i][j] = (f4){0.f, 0.f, 0.f, 0.f};

    // A staging: thread t covers row t>>1, col half (t&1)*16 (16 floats)
    const int ar = t >> 1;
    const int ac = (t & 1) * 16;
    const float* Ag = X + (size_t)(m_base + ar) * DDIM + ac;

    // B staging: 512 16B-chunks; chunk c -> Bl row c>>2, cols (c&3)*8.
    // LDS dest base must be wave-uniform; HW adds lane*16.
    unsigned short* BlBase0 = &Bl[0][0] + (size_t)(w * 64) * 8;
    unsigned short* BlBase1 = &Bl[0][0] + (size_t)(256 + w * 64) * 8;
    const int c0 = t;
    const int c1 = 256 + t;
    const unsigned short* Bg0 = Wt + (size_t)(n_base + (c0 >> 2)) * DDIM + (c0 & 3) * 8;
    const unsigned short* Bg1 = Wt + (size_t)(n_base + (c1 >> 2)) * DDIM + (c1 & 3) * 8;

    for (int kt = 0; kt < DDIM / BK; ++kt) {
        const int k0 = kt * BK;
        // A global loads issued before the barrier (no LDS hazard) to
        // overlap HBM latency with the previous iteration's MFMA.
        f4 av0 = *(const f4*)(Ag + k0 + 0);
        f4 av1 = *(const f4*)(Ag + k0 + 4);
        f4 av2 = *(const f4*)(Ag + k0 + 8);
        f4 av3 = *(const f4*)(Ag + k0 + 12);

        __syncthreads();   // previous compute done reading LDS

        __builtin_amdgcn_global_load_lds(
            (const __attribute__((address_space(1))) void*)(Bg0 + k0),
            (__attribute__((address_space(3))) void*)BlBase0, 16, 0, 0);
        __builtin_amdgcn_global_load_lds(
            (const __attribute__((address_space(1))) void*)(Bg1 + k0),
            (__attribute__((address_space(3))) void*)BlBase1, 16, 0, 0);

        s8 p0, p1;
        p0[0] = (short)f2bf(av0[0]); p0[1] = (short)f2bf(av0[1]);
        p0[2] = (short)f2bf(av0[2]); p0[3] = (short)f2bf(av0[3]);
        p0[4] = (short)f2bf(av1[0]); p0[5] = (short)f2bf(av1[1]);
        p0[6] = (short)f2bf(av1[2]); p0[7] = (short)f2bf(av1[3]);
        p1[0] = (short)f2bf(av2[0]); p1[1] = (short)f2bf(av2[1]);
        p1[2] = (short)f2bf(av2[2]); p1[3] = (short)f2bf(av2[3]);
        p1[4] = (short)f2bf(av3[0]); p1[5] = (short)f2bf(av3[1]);
        p1[6] = (short)f2bf(av3[2]); p1[7] = (short)f2bf(av3[3]);
        *(s8*)&Al[ar][ac]     = p0;   // ds_write_b128
        *(s8*)&Al[ar][ac + 8] = p1;

        __syncthreads();   // drains vmcnt (global_load_lds) + lgkmcnt

        s8 afr[4], bfr[4];
        #pragma unroll
        for (int mi = 0; mi < 4; ++mi)
            afr[mi] = *(const s8*)&Al[wr * 64 + mi * 16 + fr][fc * 8];
        #pragma unroll
        for (int ni = 0; ni < 4; ++ni)
            bfr[ni] = *(const s8*)&Bl[wc * 64 + ni * 16 + fr][fc * 8];
        #pragma unroll
        for (int mi = 0; mi < 4; ++mi)
            #pragma unroll
            for (int ni = 0; ni < 4; ++ni)
                acc[mi][ni] = __builtin_amdgcn_mfma_f32_16x16x32_bf16(
                    afr[mi], bfr[ni], acc[mi][ni], 0, 0, 0);
    }

    // Epilogue: D lane layout col = lane&15, row = (lane>>4)*4 + reg  [m89]
    const int col0 = n_base + wc * 64 + fr;
    const int row0 = m_base + wr * 64 + fc * 4;
    #pragma unroll
    for (int ni = 0; ni < 4; ++ni) {
        const int col = col0 + ni * 16;
        const float bias = beff[col];
        #pragma unroll
        for (int mi = 0; mi < 4; ++mi) {
            const int rb = row0 + mi * 16;
            #pragma unroll
            for (int r = 0; r < 4; ++r) {
                Out[(size_t)(rb + r) * DDIM + col] = acc[mi][ni][r] + bias;
            }
        }
    }
}

// ---------------------------------------------------------------------------
extern "C" void kernel_launch(void* const* d_in, const int* in_sizes, int n_in,
                              void* d_out, int out_size, void* d_ws, size_t ws_size,
                              hipStream_t stream) {
    const float* X      = (const float*)d_in[0];  // [32,2048,512]
    const float* logits = (const float*)d_in[1];  // [26,26]
    const float* fp_w   = (const float*)d_in[2];  // [26,512]
    const float* fp_b   = (const float*)d_in[3];  // [26]
    const float* op_w   = (const float*)d_in[4];  // [512,26]
    const float* op_b   = (const float*)d_in[5];  // [512]
    float* out = (float*)d_out;

    // workspace layout (needs ~533 KB)
    char* ws = (char*)d_ws;
    unsigned short* Wt = (unsigned short*)ws;                 // 512*512*2 = 524288
    float* beff = (float*)(ws + 524288);                      // 2 KB
    float* Pm   = (float*)(ws + 524288 + 4096);               // 26*26*4
    float* pb   = (float*)(ws + 524288 + 8192);               // 26*4

    perm_sinkhorn_kernel<<<1, 64, 0, stream>>>(logits, fp_b, Pm, pb);
    weff_kernel<<<512, 512, 0, stream>>>(fp_w, op_w, op_b, Pm, pb, Wt, beff);
    gemm_kernel<<<2048, 256, 0, stream>>>(X, Wt, beff, out);
}

// Round 4
// 317.527 us; speedup vs baseline: 1.0361x; 1.0361x over previous
//
#include <hip/hip_runtime.h>
#include <stdint.h>

// Problem constants
#define PSIZE 26
#define DDIM  512
#define NTOK  65536   // B*S = 32*2048
#define NIT   50
#define SEPS  1e-8f

// GEMM tiling
#define BM 128
#define BN 128
#define BK 32

typedef __attribute__((ext_vector_type(4))) float f4;
typedef __attribute__((ext_vector_type(8))) short s8;   // 8 bf16 (4 VGPRs), MFMA A/B frag

// RTNE f32 -> bf16 (bit pattern) — used only in tiny weff kernel
__device__ __forceinline__ unsigned short f2bf(float f) {
    unsigned int u = __builtin_bit_cast(unsigned int, f);
    u = u + 0x7fffu + ((u >> 16) & 1u);
    return (unsigned short)(u >> 16);
}

// ---------------------------------------------------------------------------
// Kernel 1: softmax(logits) + 50 Sinkhorn iters (26x26) + pb = P @ fp_b
// Single wave, shuffle-only iteration: P_t = diag(u) S diag(v).
//   row pass: rowsum_i = u_i*(S v)_i;  u <- u/(rowsum+eps)
//   col pass: colsum_k = v_k*(S^T u)_k; v <- v/(colsum+eps)
// (S v)_i via 26 __shfl broadcasts of v; S^T held per-lane (built once via LDS).
// No barriers, no LDS in the 50-iter loop -> ~5 us instead of ~20.
// ---------------------------------------------------------------------------
__global__ void perm_sinkhorn_kernel(const float* __restrict__ logits,
                                     const float* __restrict__ fp_b,
                                     float* __restrict__ P_out,   // [26*26]
                                     float* __restrict__ pb_out)  // [26]
{
    __shared__ float Sh[PSIZE][PSIZE + 1];
    const int l = threadIdx.x;
    float s[PSIZE];   // row l of S (softmax)
    float st[PSIZE];  // col l of S
    #pragma unroll
    for (int c = 0; c < PSIZE; ++c) { s[c] = 0.f; st[c] = 0.f; }

    if (l < PSIZE) {
        float mx = -1e30f;
        #pragma unroll
        for (int c = 0; c < PSIZE; ++c) { s[c] = logits[l * PSIZE + c]; mx = fmaxf(mx, s[c]); }
        float sum = 0.f;
        #pragma unroll
        for (int c = 0; c < PSIZE; ++c) { s[c] = expf(s[c] - mx); sum += s[c]; }
        float inv = 1.f / sum;
        #pragma unroll
        for (int c = 0; c < PSIZE; ++c) { s[c] *= inv; Sh[l][c] = s[c]; }
    }
    __syncthreads();
    if (l < PSIZE) {
        #pragma unroll
        for (int i = 0; i < PSIZE; ++i) st[i] = Sh[i][l];
    }

    float u = 1.f, v = 1.f;
    float fb = (l < PSIZE) ? fp_b[l] : 0.f;

    for (int it = 0; it < NIT; ++it) {
        float sv = 0.f;
        #pragma unroll
        for (int k = 0; k < PSIZE; ++k) sv += s[k] * __shfl(v, k);
        u = u / (u * sv + SEPS);
        float stu = 0.f;
        #pragma unroll
        for (int i = 0; i < PSIZE; ++i) stu += st[i] * __shfl(u, i);
        v = v / (v * stu + SEPS);
    }

    const float vf = v * fb;
    if (l < PSIZE) {
        float pbv = 0.f;
        #pragma unroll
        for (int k = 0; k < PSIZE; ++k) pbv += s[k] * __shfl(vf, k);
        pb_out[l] = u * pbv;
        #pragma unroll
        for (int c = 0; c < PSIZE; ++c)
            P_out[l * PSIZE + c] = u * s[c] * __shfl(v, c);
    }
}

// ---------------------------------------------------------------------------
// Kernel 2: fold small matrices into effective 512x512 weight, stored in the
// GEMM's pre-swizzled staging layout:
//   Wt_staged[nb][kt][row*4 + (kc ^ ((row>>1)&3))][e] = Weff[nb*128+row][kt*32+kc*8+e]
// so that linear global_load_lds + XOR-swizzled ds_read is bank-conflict-free
// (rule #21: swizzle source + read, keep LDS dest linear).
//   g[n][k]  = sum_j op_w[n][j] * P[j][k]
//   Weff[n][d] = sum_k g[n][k] * fp_w[k][d]
//   beff[n]  = sum_j pb[j] * op_w[n][j] + op_b[n]
// ---------------------------------------------------------------------------
__global__ __launch_bounds__(512)
void weff_kernel(const float* __restrict__ fp_w,   // [26][512]
                 const float* __restrict__ op_w,   // [512][26]
                 const float* __restrict__ op_b,   // [512]
                 const float* __restrict__ Pm,     // [26][26]
                 const float* __restrict__ pb,     // [26]
                 unsigned short* __restrict__ Wt,  // staged [4][16][512][8] bf16 bits
                 float* __restrict__ beff)         // [512]
{
    const int n = blockIdx.x;
    const int t = threadIdx.x;    // = d
    __shared__ float ow[PSIZE];
    __shared__ float g[PSIZE];
    if (t < PSIZE) ow[t] = op_w[n * PSIZE + t];
    __syncthreads();
    if (t < PSIZE) {
        float sg = 0.f;
        #pragma unroll
        for (int j = 0; j < PSIZE; ++j) sg += ow[j] * Pm[j * PSIZE + t];
        g[t] = sg;
    }
    __syncthreads();
    float acc = 0.f;
    #pragma unroll
    for (int k = 0; k < PSIZE; ++k) acc += g[k] * fp_w[k * DDIM + t];

    const int nb  = n >> 7;
    const int row = n & 127;
    const int kt  = t >> 5;
    const int kc  = (t >> 3) & 3;
    const int e   = t & 7;
    const int sc  = kc ^ ((row >> 1) & 3);
    Wt[(((size_t)(nb * 16 + kt) * 512) + row * 4 + sc) * 8 + e] = f2bf(acc);

    if (t == 0) {
        float sb = 0.f;
        #pragma unroll
        for (int j = 0; j < PSIZE; ++j) sb += pb[j] * ow[j];
        beff[n] = sb + op_b[n];
    }
}

// ---------------------------------------------------------------------------
// Kernel 3: Out[65536][512] = X @ W_eff + beff  (bf16 MFMA, f32 in/out)
// 128x128 tile, 4 waves, BK=32, 16x16x32 MFMA.
// A: reg-staged, v_cvt_pk_bf16_f32, XOR-swizzled ds_write; next-iter loads
//    issued after barrier #2 so MFMA covers their latency.
// B: global_load_lds width=16 from the pre-swizzled Wt staging buffer.
// LDS chunk swizzle: chunk' = chunk ^ ((row>>1)&3) -> each quarter-wave's 16
// ds_read_b128 lanes cover all 8 16B-slots exactly twice (conflict-free).
// ---------------------------------------------------------------------------
__global__ __launch_bounds__(256)
void gemm_kernel(const float* __restrict__ X,            // [65536][512] f32
                 const unsigned short* __restrict__ Wt,  // staged bf16
                 const float* __restrict__ beff,         // [512]
                 float* __restrict__ Out)                 // [65536][512] f32
{
    __shared__ alignas(16) unsigned short Al[BM][BK];  // 8 KiB
    __shared__ alignas(16) unsigned short Bl[BN][BK];  // 8 KiB

    const int bid = blockIdx.x;
    // bijective XCD swizzle: 2048 blocks, 8 XCDs, 256-block chunks; N-fastest
    const int lg = (bid & 7) * 256 + (bid >> 3);
    const int nb = lg & 3;
    const int mb = lg >> 2;
    const int m_base = mb * BM;
    const int n_base = nb * BN;

    const int t    = threadIdx.x;
    const int lane = t & 63;
    const int w    = t >> 6;
    const int wr   = w >> 1;
    const int wc   = w & 1;
    const int fr   = lane & 15;
    const int fc   = lane >> 4;
    const int frs  = fc ^ ((fr >> 1) & 3);   // swizzled chunk for frag reads

    f4 acc[4][4];
    #pragma unroll
    for (int i = 0; i < 4; ++i)
        #pragma unroll
        for (int j = 0; j < 4; ++j)
            acc[i][j] = (f4){0.f, 0.f, 0.f, 0.f};

    // A staging: thread t covers row t>>1, float cols (t&1)*16 .. +15
    const int ar  = t >> 1;
    const int acH = t & 1;
    const float* Ag = X + (size_t)(m_base + ar) * DDIM + acH * 16;
    const int wsc0 = (2 * acH)     ^ ((ar >> 1) & 3);
    const int wsc1 = (2 * acH + 1) ^ ((ar >> 1) & 3);
    unsigned short* Aw0 = &Al[ar][wsc0 * 8];
    unsigned short* Aw1 = &Al[ar][wsc1 * 8];

    // B staging: chunk c (16B) -> LDS linear offset c*16. Wave-uniform bases.
    unsigned short* BlB0 = &Bl[0][0] + (size_t)(w * 64) * 8;
    unsigned short* BlB1 = &Bl[0][0] + (size_t)(256 + w * 64) * 8;
    const unsigned short* Bg0 = Wt + (size_t)nb * 65536 + (size_t)t * 8;
    const unsigned short* Bg1 = Wt + (size_t)nb * 65536 + (size_t)(256 + t) * 8;

    // prologue: load A tile 0
    f4 a0 = *(const f4*)(Ag + 0);
    f4 a1 = *(const f4*)(Ag + 4);
    f4 a2 = *(const f4*)(Ag + 8);
    f4 a3 = *(const f4*)(Ag + 12);

    for (int kt = 0; kt < DDIM / BK; ++kt) {
        __syncthreads();   // prev iteration's LDS reads complete

        __builtin_amdgcn_global_load_lds(
            (const __attribute__((address_space(1))) void*)(Bg0 + kt * 4096),
            (__attribute__((address_space(3))) void*)BlB0, 16, 0, 0);
        __builtin_amdgcn_global_load_lds(
            (const __attribute__((address_space(1))) void*)(Bg1 + kt * 4096),
            (__attribute__((address_space(3))) void*)BlB1, 16, 0, 0);

        // f32 -> packed bf16 via v_cvt_pk_bf16_f32 (1 instr / 2 elems)
        union { s8 v; unsigned int u[4]; } p0, p1;
        asm("v_cvt_pk_bf16_f32 %0, %1, %2" : "=v"(p0.u[0]) : "v"(a0[0]), "v"(a0[1]));
        asm("v_cvt_pk_bf16_f32 %0, %1, %2" : "=v"(p0.u[1]) : "v"(a0[2]), "v"(a0[3]));
        asm("v_cvt_pk_bf16_f32 %0, %1, %2" : "=v"(p0.u[2]) : "v"(a1[0]), "v"(a1[1]));
        asm("v_cvt_pk_bf16_f32 %0, %1, %2" : "=v"(p0.u[3]) : "v"(a1[2]), "v"(a1[3]));
        asm("v_cvt_pk_bf16_f32 %0, %1, %2" : "=v"(p1.u[0]) : "v"(a2[0]), "v"(a2[1]));
        asm("v_cvt_pk_bf16_f32 %0, %1, %2" : "=v"(p1.u[1]) : "v"(a2[2]), "v"(a2[3]));
        asm("v_cvt_pk_bf16_f32 %0, %1, %2" : "=v"(p1.u[2]) : "v"(a3[0]), "v"(a3[1]));
        asm("v_cvt_pk_bf16_f32 %0, %1, %2" : "=v"(p1.u[3]) : "v"(a3[2]), "v"(a3[3]));
        *(s8*)Aw0 = p0.v;
        *(s8*)Aw1 = p1.v;

        __syncthreads();   // drains B gload_lds + A ds_write

        // issue next A tile now: MFMA phase hides the HBM latency; last iter
        // re-loads the current (L1-hot) tile to stay branch-free and in-bounds
        const float* An = Ag + ((kt < 15) ? (kt + 1) * BK : kt * BK);
        f4 n0 = *(const f4*)(An + 0);
        f4 n1 = *(const f4*)(An + 4);
        f4 n2 = *(const f4*)(An + 8);
        f4 n3 = *(const f4*)(An + 12);

        s8 afr[4], bfr[4];
        #pragma unroll
        for (int mi = 0; mi < 4; ++mi)
            afr[mi] = *(const s8*)&Al[wr * 64 + mi * 16 + fr][frs * 8];
        #pragma unroll
        for (int ni = 0; ni < 4; ++ni)
            bfr[ni] = *(const s8*)&Bl[wc * 64 + ni * 16 + fr][frs * 8];
        #pragma unroll
        for (int mi = 0; mi < 4; ++mi)
            #pragma unroll
            for (int ni = 0; ni < 4; ++ni)
                acc[mi][ni] = __builtin_amdgcn_mfma_f32_16x16x32_bf16(
                    afr[mi], bfr[ni], acc[mi][ni], 0, 0, 0);

        a0 = n0; a1 = n1; a2 = n2; a3 = n3;
    }

    // Epilogue: D lane layout col = lane&15, row = (lane>>4)*4 + reg  [m89]
    const int col0 = n_base + wc * 64 + fr;
    const int row0 = m_base + wr * 64 + fc * 4;
    #pragma unroll
    for (int ni = 0; ni < 4; ++ni) {
        const int col = col0 + ni * 16;
        const float bias = beff[col];
        #pragma unroll
        for (int mi = 0; mi < 4; ++mi) {
            const int rb = row0 + mi * 16;
            #pragma unroll
            for (int r = 0; r < 4; ++r) {
                Out[(size_t)(rb + r) * DDIM + col] = acc[mi][ni][r] + bias;
            }
        }
    }
}

// ---------------------------------------------------------------------------
extern "C" void kernel_launch(void* const* d_in, const int* in_sizes, int n_in,
                              void* d_out, int out_size, void* d_ws, size_t ws_size,
                              hipStream_t stream) {
    const float* X      = (const float*)d_in[0];  // [32,2048,512]
    const float* logits = (const float*)d_in[1];  // [26,26]
    const float* fp_w   = (const float*)d_in[2];  // [26,512]
    const float* fp_b   = (const float*)d_in[3];  // [26]
    const float* op_w   = (const float*)d_in[4];  // [512,26]
    const float* op_b   = (const float*)d_in[5];  // [512]
    float* out = (float*)d_out;

    // workspace layout (needs ~533 KB)
    char* ws = (char*)d_ws;
    unsigned short* Wt = (unsigned short*)ws;                 // 512*512*2 = 524288
    float* beff = (float*)(ws + 524288);                      // 2 KB
    float* Pm   = (float*)(ws + 524288 + 4096);               // 26*26*4
    float* pb   = (float*)(ws + 524288 + 8192);               // 26*4

    perm_sinkhorn_kernel<<<1, 64, 0, stream>>>(logits, fp_b, Pm, pb);
    weff_kernel<<<512, 512, 0, stream>>>(fp_w, op_w, op_b, Pm, pb, Wt, beff);
    gemm_kernel<<<2048, 256, 0, stream>>>(X, Wt, beff, out);
}